// Round 1
// 397.464 us; speedup vs baseline: 1.0234x; 1.0234x over previous
//
#include <hip/hip_runtime.h>
#include <hip/hip_bf16.h>
#include <hip/hip_fp16.h>

#define SEQ 1024
#define HEADS 16
#define HDIM 64
#define EMB 1024
#define TQ 32            // q rows per attention block (2 row-tiles)
#define KQ 256           // k per quarter (split-K/4)
#define PBA_S 264        // PbA row stride (u16): 256+8
#define PBB_S 328        // PbB row stride (u16): window<=295 + read slack -> 328
#define RELK_ROWS 1040   // 1025 real + zero pad
#define RELV_S 1064      // relv^T padded col stride (zeros past 1024)

typedef __bf16 bf16x8 __attribute__((ext_vector_type(8)));
typedef float floatx4 __attribute__((ext_vector_type(4)));
typedef unsigned short u16x4 __attribute__((ext_vector_type(4)));

#if __has_builtin(__builtin_amdgcn_exp2f)
#define EXP2F(x) __builtin_amdgcn_exp2f(x)
#else
#define EXP2F(x) exp2f(x)
#endif

// scores are pre-scaled by log2(e)/8 in the Q projection so softmax uses exp2
#define QSCALE 0.18033688011112042f

static __device__ __forceinline__ unsigned short f2bu(float f) {
    __bf16 h = (__bf16)f;
    return __builtin_bit_cast(unsigned short, h);
}
static __device__ __forceinline__ float b2f(unsigned short u) {
    unsigned v = ((unsigned)u) << 16;
    return __builtin_bit_cast(float, v);
}

// ---------------------------------------------------------------------------
// Kernel 1: MFMA projections. grid (1024, 3): bx>>2 -> 16-row tile, bx&3 ->
// head group; each wave handles ONE head. Depends on sa_prep_kernel.
// Q is scaled by log2(e)/8 (exp2-based softmax downstream).
// ---------------------------------------------------------------------------
__global__ __launch_bounds__(256) void sa_proj_kernel(
    const float* __restrict__ qin, const float* __restrict__ kin,
    const float* __restrict__ vin,
    const unsigned short* __restrict__ wqb, const unsigned short* __restrict__ wkb,
    const unsigned short* __restrict__ wvb,
    const float* __restrict__ bq, const float* __restrict__ bk,
    const float* __restrict__ bv_,
    unsigned short* __restrict__ qb, unsigned short* __restrict__ kb,
    unsigned short* __restrict__ vtb) {
    const int t = threadIdx.x;
    const int w = t >> 6, lane = t & 63;
    const int quad = lane >> 4, l16 = lane & 15;
    const int which = blockIdx.y;
    const int bx = blockIdx.x;
    const int r0 = (bx >> 2) * 16;
    const int h = (bx & 3) * 4 + w;
    const int bidx = r0 >> 10;
    const int l0 = r0 & 1023;
    const float* x = (which == 0) ? qin : (which == 1) ? kin : vin;
    const unsigned short* Wb = (which == 0) ? wqb : (which == 1) ? wkb : wvb;
    const float* bias = (which == 0) ? bq : (which == 1) ? bk : bv_;

    bf16x8 wf[4][2];
#pragma unroll
    for (int dt = 0; dt < 4; ++dt)
#pragma unroll
        for (int ks = 0; ks < 2; ++ks)
            wf[dt][ks] = *(const bf16x8*)(Wb + (size_t)(dt * 16 + l16) * 64 + ks * 32 + quad * 8);

    bf16x8 xf[2];
#pragma unroll
    for (int ks = 0; ks < 2; ++ks) {
        const float* xp = x + (size_t)(r0 + l16) * EMB + h * 64 + ks * 32 + quad * 8;
        float4 lo = *(const float4*)xp;
        float4 hi = *(const float4*)(xp + 4);
        unsigned short px[8];
        px[0] = f2bu(lo.x); px[1] = f2bu(lo.y); px[2] = f2bu(lo.z); px[3] = f2bu(lo.w);
        px[4] = f2bu(hi.x); px[5] = f2bu(hi.y); px[6] = f2bu(hi.z); px[7] = f2bu(hi.w);
        xf[ks] = *(bf16x8*)px;
    }
    const int bh = bidx * HEADS + h;

    if (which < 2) {
        float biasd[4];
#pragma unroll
        for (int dt = 0; dt < 4; ++dt) biasd[dt] = bias[dt * 16 + l16];
        const float sc = (which == 0) ? QSCALE : 1.0f;
        unsigned short* dst = (which == 0) ? qb : kb;
        floatx4 acc[4];
#pragma unroll
        for (int dt = 0; dt < 4; ++dt) acc[dt] = floatx4{0.f, 0.f, 0.f, 0.f};
#pragma unroll
        for (int dt = 0; dt < 4; ++dt)
#pragma unroll
            for (int ks = 0; ks < 2; ++ks)
                acc[dt] = __builtin_amdgcn_mfma_f32_16x16x32_bf16(xf[ks], wf[dt][ks], acc[dt], 0, 0, 0);
#pragma unroll
        for (int dt = 0; dt < 4; ++dt)
#pragma unroll
            for (int i = 0; i < 4; ++i) {
                const int lr = l0 + quad * 4 + i;
                float val = (acc[dt][i] + biasd[dt]) * sc;
                dst[((size_t)bh * SEQ + lr) * 64 + dt * 16 + l16] = f2bu(val);
            }
    } else {
        float biasv[4][4];
#pragma unroll
        for (int dt = 0; dt < 4; ++dt)
#pragma unroll
            for (int i = 0; i < 4; ++i) biasv[dt][i] = bias[dt * 16 + quad * 4 + i];
        floatx4 acc[4];
#pragma unroll
        for (int dt = 0; dt < 4; ++dt) acc[dt] = floatx4{0.f, 0.f, 0.f, 0.f};
        // v transposed: A = Wv rows (d), B = X rows (l) -> C[d][l]
#pragma unroll
        for (int dt = 0; dt < 4; ++dt)
#pragma unroll
            for (int ks = 0; ks < 2; ++ks)
                acc[dt] = __builtin_amdgcn_mfma_f32_16x16x32_bf16(wf[dt][ks], xf[ks], acc[dt], 0, 0, 0);
#pragma unroll
        for (int dt = 0; dt < 4; ++dt)
#pragma unroll
            for (int i = 0; i < 4; ++i) {
                const int d = dt * 16 + quad * 4 + i;
                float val = acc[dt][i] + biasv[dt][i];
                vtb[((size_t)bh * 64 + d) * SEQ + l0 + l16] = f2bu(val);
            }
    }
}

// ---------------------------------------------------------------------------
// Kernel 2: prep (bf16 conversions/padding) + mask all-ones partial reduction.
// ---------------------------------------------------------------------------
#define NW (1024 * 1024)
#define NRK (RELK_ROWS * 64)
#define NRV (64 * RELV_S)
#define NWP (3 * 4096)
#define CONV_BLOCKS ((NW + NRK + NRV + NWP) / 256)   // = 4670 exactly
__global__ __launch_bounds__(256) void sa_prep_kernel(
    const float* __restrict__ Wfc, const float* __restrict__ relk,
    const float* __restrict__ relv,
    const float* __restrict__ Wq, const float* __restrict__ Wk,
    const float* __restrict__ Wv, const int* __restrict__ mask,
    unsigned short* __restrict__ wfcb, unsigned short* __restrict__ relkb,
    unsigned short* __restrict__ relvtb,
    unsigned short* __restrict__ wqb, unsigned short* __restrict__ wkb,
    unsigned short* __restrict__ wvb, unsigned* __restrict__ part) {
    const int bx = blockIdx.x;
    const int t = threadIdx.x;
    if (bx < CONV_BLOCKS) {
        int i = bx * 256 + t;
        if (i < NW) {
            wfcb[i] = f2bu(Wfc[i]);
        } else if (i < NW + NRK) {
            int j = i - NW;
            int r = j >> 6, d = j & 63;
            relkb[j] = (r <= 1024) ? f2bu(relk[r * 64 + d]) : 0;
        } else if (i < NW + NRK + NRV) {
            int j = i - NW - NRK;
            int d = j / RELV_S, c = j - d * RELV_S;
            relvtb[j] = (c <= 1024) ? f2bu(relv[c * 64 + d]) : 0;
        } else {
            int j = i - NW - NRK - NRV;
            int which = j >> 12, e = j & 4095;
            const float* src = (which == 0) ? Wq : (which == 1) ? Wk : Wv;
            unsigned short* dst = (which == 0) ? wqb : (which == 1) ? wkb : wvb;
            dst[e] = f2bu(src[e]);
        }
    } else {
        const int mb = bx - CONV_BLOCKS;
        const int b = mb >> 6, chunk = mb & 63;
        const int4* p = (const int4*)(mask + (size_t)b * (SEQ * SEQ) + chunk * 16384);
        int ok = 1;
#pragma unroll
        for (int i = 0; i < 16; ++i) {
            int4 v = p[t + i * 256];
            ok &= (v.x != 0 && v.y != 0 && v.z != 0 && v.w != 0) ? 1 : 0;
        }
        unsigned long long bal = __ballot(ok);
        __shared__ unsigned wok[4];
        if ((t & 63) == 0) wok[t >> 6] = (bal == ~0ull) ? 1u : 0u;
        __syncthreads();
        if (t == 0)
            part[b * 64 + chunk] = (wok[0] & wok[1] & wok[2] & wok[3]) ? 0xFFFFFFFFu : 0u;
    }
}

__global__ void sa_maskred2(const unsigned* __restrict__ part, unsigned* __restrict__ flags) {
    int t = threadIdx.x;
    if (t < 4) {
        unsigned f = 0xFFFFFFFFu;
        for (int i = 0; i < 64; ++i) f &= part[t * 64 + i];
        flags[t] = f;
    }
}

// ---------------------------------------------------------------------------
// Kernel 3: quarter-K MFMA attention, SWAPPED-OPERAND form.
// 8192 blocks (bh x 32 qtiles x 4 quarters), 512 thr (8 waves).
// Phase C computes S^T = mfma(K, Q): lane holds q = l16 (per rt), k =
// quad*4+i (per tt). Row-reductions become in-lane + 2 shuffles; P stores
// pack to b64 along k; row-sums/tails are computed in Phase F via an extra
// mfma(P, ones) per subtile (accS/accSI), removing the shuffle-based
// ssum/tail reductions, two wred arrays and one barrier.
// LDS 39040 B -> 4 blocks/CU. 4 barriers.
// ---------------------------------------------------------------------------
__global__ __launch_bounds__(512, 8) void sa_attn_kernel(
    const unsigned short* __restrict__ qb, const unsigned short* __restrict__ kb,
    const unsigned short* __restrict__ vtb, const int* __restrict__ mask,
    const unsigned short* __restrict__ relkb, const unsigned short* __restrict__ relvtb,
    const unsigned* __restrict__ flags, __half* __restrict__ Opart,
    float2* __restrict__ ms) {
    __shared__ __align__(16) unsigned short PbA[TQ * PBA_S];  // 16896 B, P in k-layout
    __shared__ __align__(16) unsigned short PbB[TQ * PBB_S];  // 20992 B, RS then P in c-layout
    __shared__ float mxpart[8 * TQ];                          // 1024 B, [kc][row]
    __shared__ float mxS[TQ];                                 // 128 B

    const int tid = threadIdx.x;
    const int w = tid >> 6, lane = tid & 63;
    const int quad = lane >> 4, l16 = lane & 15;
    const int bid = blockIdx.x;
    const int quarter = bid & 3;
    const int qt = (bid >> 2) & 31;
    const int bh = bid >> 7;
    const int q0 = qt * TQ;
    const int k0 = quarter * KQ;
    const int b = bh >> 4;
    const bool mfull = (flags[b] == 0xFFFFFFFFu);
    // block clips only if some |k-q| > 512 (boundary |k-q|==512 needs no clip)
    const bool clipped = (k0 - (q0 + 31) < -512) || (k0 + 255 - q0 > 512);

    // c-window: c = clip(k-q,±512)+512, width <= 287
    const int cmin = min(512, max(-512, k0 - (q0 + 31))) + 512;
    const int cmax = min(512, max(-512, k0 + 255 - q0)) + 512;
    const int rsb = cmin & ~15;   // RS storage base (16-aligned)
    const int cb0 = cmin & ~7;    // PbB storage base (16B-aligned)

    // Q B-fragments for BOTH row-tiles (lane l16 = q row within tile)
    bf16x8 aq[2][2];
#pragma unroll
    for (int rt = 0; rt < 2; ++rt) {
        const unsigned short* qrow = qb + ((size_t)bh * SEQ + q0 + rt * 16 + l16) * 64;
        aq[rt][0] = *(const bf16x8*)(qrow + quad * 8);
        aq[rt][1] = *(const bf16x8*)(qrow + 32 + quad * 8);
    }

    // ---- Phase B: RS^T = mfma(relk, Q) over window -> PbB[q][c], c contiguous
    // along i => packed b64 stores (offset ct*16+quad*4-rsb is 4-aligned). ----
    {
        const int ct_lo = cmin >> 4, ct_hi = cmax >> 4;
        for (int ct = ct_lo + w; ct <= ct_hi; ct += 8) {
            bf16x8 bf0 = *(const bf16x8*)(relkb + (size_t)(ct * 16 + l16) * 64 + quad * 8);
            bf16x8 bf1 = *(const bf16x8*)(relkb + (size_t)(ct * 16 + l16) * 64 + 32 + quad * 8);
            floatx4 r0 = {0.f, 0.f, 0.f, 0.f}, r1 = {0.f, 0.f, 0.f, 0.f};
            r0 = __builtin_amdgcn_mfma_f32_16x16x32_bf16(bf0, aq[0][0], r0, 0, 0, 0);
            r0 = __builtin_amdgcn_mfma_f32_16x16x32_bf16(bf1, aq[0][1], r0, 0, 0, 0);
            r1 = __builtin_amdgcn_mfma_f32_16x16x32_bf16(bf0, aq[1][0], r1, 0, 0, 0);
            r1 = __builtin_amdgcn_mfma_f32_16x16x32_bf16(bf1, aq[1][1], r1, 0, 0, 0);
            const int co = ct * 16 + quad * 4 - rsb;   // mult of 4, fits slack
            u16x4 p0, p1;
#pragma unroll
            for (int i = 0; i < 4; ++i) { p0[i] = f2bu(r0[i]); p1[i] = f2bu(r1[i]); }
            *(u16x4*)&PbB[(size_t)l16 * PBB_S + co] = p0;
            *(u16x4*)&PbB[(size_t)(16 + l16) * PBB_S + co] = p1;
        }
    }
    __syncthreads();   // (1)

    // ---- Phase C: S^T = mfma(K, Q); lane: q = q0+rt*16+l16, k = k0+kc*32+
    // tt*16+quad*4+i. RS gather reads PbB[q][c-rsb]. ----
    const int kc = w;               // 32-col k chunk
    const int qg[2] = {q0 + l16, q0 + 16 + l16};
    floatx4 acc[2][2];              // [rt][tt]
#pragma unroll
    for (int rt = 0; rt < 2; ++rt)
#pragma unroll
        for (int tt = 0; tt < 2; ++tt) acc[rt][tt] = floatx4{0.f, 0.f, 0.f, 0.f};
#pragma unroll
    for (int tt = 0; tt < 2; ++tt) {
        const unsigned short* krow = kb + ((size_t)bh * SEQ + k0 + kc * 32 + tt * 16 + l16) * 64;
        bf16x8 kf0 = *(const bf16x8*)(krow + quad * 8);
        bf16x8 kf1 = *(const bf16x8*)(krow + 32 + quad * 8);
        acc[0][tt] = __builtin_amdgcn_mfma_f32_16x16x32_bf16(kf0, aq[0][0], acc[0][tt], 0, 0, 0);
        acc[0][tt] = __builtin_amdgcn_mfma_f32_16x16x32_bf16(kf1, aq[0][1], acc[0][tt], 0, 0, 0);
        acc[1][tt] = __builtin_amdgcn_mfma_f32_16x16x32_bf16(kf0, aq[1][0], acc[1][tt], 0, 0, 0);
        acc[1][tt] = __builtin_amdgcn_mfma_f32_16x16x32_bf16(kf1, aq[1][1], acc[1][tt], 0, 0, 0);
    }
    float rmax2[2] = {-3.0e38f, -3.0e38f};
    if (mfull) {
        if (!clipped) {
#pragma unroll
            for (int rt = 0; rt < 2; ++rt) {
                const unsigned short* rsrow = &PbB[(size_t)(rt * 16 + l16) * PBB_S];
                const int cb = k0 + kc * 32 - qg[rt] + 512 - rsb;
#pragma unroll
                for (int tt = 0; tt < 2; ++tt)
#pragma unroll
                    for (int i = 0; i < 4; ++i) {
                        float s = acc[rt][tt][i] + b2f(rsrow[cb + tt * 16 + quad * 4 + i]);
                        acc[rt][tt][i] = s;
                        rmax2[rt] = fmaxf(rmax2[rt], s);
                    }
            }
        } else {
#pragma unroll
            for (int rt = 0; rt < 2; ++rt) {
                const unsigned short* rsrow = &PbB[(size_t)(rt * 16 + l16) * PBB_S];
                const int cb = k0 + kc * 32 - qg[rt] + 512;
#pragma unroll
                for (int tt = 0; tt < 2; ++tt)
#pragma unroll
                    for (int i = 0; i < 4; ++i) {
                        const int c = cb + tt * 16 + quad * 4 + i;
                        const int r = min(1024, max(0, c));
                        float s = acc[rt][tt][i] + b2f(rsrow[r - rsb]);
                        acc[rt][tt][i] = s;
                        rmax2[rt] = fmaxf(rmax2[rt], s);
                    }
            }
        }
    } else {
#pragma unroll
        for (int rt = 0; rt < 2; ++rt) {
            const unsigned short* rsrow = &PbB[(size_t)(rt * 16 + l16) * PBB_S];
            const int q = qg[rt];
            const int cb = k0 + kc * 32 - q + 512;
            const int* mrow = mask + (size_t)b * (SEQ * SEQ) + (size_t)q * SEQ;
#pragma unroll
            for (int tt = 0; tt < 2; ++tt)
#pragma unroll
                for (int i = 0; i < 4; ++i) {
                    const int k = k0 + kc * 32 + tt * 16 + quad * 4 + i;
                    const int c = cb + tt * 16 + quad * 4 + i;
                    const int r = min(1024, max(0, c));
                    float s = acc[rt][tt][i] + b2f(rsrow[r - rsb]);
                    int m = mrow[k];
                    s = (m == 0) ? -1e20f : s;
                    acc[rt][tt][i] = s;
                    rmax2[rt] = fmaxf(rmax2[rt], s);
                }
        }
    }
    // in-lane 8-way max done above; finish across quads (k direction)
#pragma unroll
    for (int rt = 0; rt < 2; ++rt) {
        rmax2[rt] = fmaxf(rmax2[rt], __shfl_xor(rmax2[rt], 16));
        rmax2[rt] = fmaxf(rmax2[rt], __shfl_xor(rmax2[rt], 32));
    }
    if (quad == 0) {
        mxpart[kc * 32 + l16] = rmax2[0];
        mxpart[kc * 32 + 16 + l16] = rmax2[1];
    }
    __syncthreads();   // (2)

    // ---- zero-fill PbB (RS dead) + finalize row max -> mxS ----
    if (tid < TQ) {
        float m = mxpart[tid];
#pragma unroll
        for (int j = 1; j < 8; ++j) m = fmaxf(m, mxpart[j * 32 + tid]);
        mxS[tid] = m;
    }
    for (int g = tid; g < TQ * (PBB_S / 8); g += 512) {
        int row = g / (PBB_S / 8), j = g - row * (PBB_S / 8);
        *(uint4*)&PbB[row * PBB_S + j * 8] = make_uint4(0u, 0u, 0u, 0u);
    }
    __syncthreads();   // (3)

    // ---- Phase D: exp2 + dual P store (PbA packed b64; PbB skewed u16) ----
    {
        const float mxv[2] = {mxS[l16], mxS[16 + l16]};
#pragma unroll
        for (int rt = 0; rt < 2; ++rt) {
            unsigned short* parow = &PbA[(size_t)(rt * 16 + l16) * PBA_S + kc * 32];
            unsigned short* pbrow = &PbB[(size_t)(rt * 16 + l16) * PBB_S];
            const int cbase = k0 + kc * 32 - qg[rt] + 512;
#pragma unroll
            for (int tt = 0; tt < 2; ++tt) {
                u16x4 pk;
#pragma unroll
                for (int i = 0; i < 4; ++i)
                    pk[i] = f2bu(EXP2F(acc[rt][tt][i] - mxv[rt]));
                *(u16x4*)(parow + tt * 16 + quad * 4) = pk;
                const int c0 = cbase + tt * 16 + quad * 4;
                if (!clipped) {
#pragma unroll
                    for (int i = 0; i < 4; ++i) pbrow[c0 + i - cb0] = pk[i];
                } else {
#pragma unroll
                    for (int i = 0; i < 4; ++i) {
                        const int c = c0 + i;
                        if ((unsigned)(c - 1) < 1023u) pbrow[c - cb0] = pk[i];
                    }
                }
            }
        }
    }
    __syncthreads();   // (4)

    // ---- Phase F: wave (rt, dq) owns full 256-k quarter. Row-sums via
    // mfma(P, ones): accS (total, from PbA) and accSI (interior, from PbB);
    // tail = accS - accSI replaces the old shuffle/LDS tail reduction. ----
    {
        const int rt = w & 1;
        const int dq = w >> 1;
        floatx4 accA = {0.f, 0.f, 0.f, 0.f};
        floatx4 accB = {0.f, 0.f, 0.f, 0.f};
        floatx4 accS = {0.f, 0.f, 0.f, 0.f};
        floatx4 accSI = {0.f, 0.f, 0.f, 0.f};
        unsigned short ob[8];
#pragma unroll
        for (int j = 0; j < 8; ++j) ob[j] = 0x3F80;   // bf16 1.0
        const bf16x8 onesf = *(bf16x8*)ob;
        const unsigned short* vbase = vtb + ((size_t)bh * 64 + dq * 16 + l16) * SEQ + k0;
        const unsigned short* rbase = relvtb + (size_t)(dq * 16 + l16) * RELV_S;
#pragma unroll
        for (int it = 0; it < 8; ++it) {
            const int co = it * 32 + quad * 8;
            bf16x8 ap = *(const bf16x8*)&PbA[(size_t)(rt * 16 + l16) * PBA_S + co];
            bf16x8 bv = *(const bf16x8*)(vbase + co);
            accA = __builtin_amdgcn_mfma_f32_16x16x32_bf16(ap, bv, accA, 0, 0, 0);
            accS = __builtin_amdgcn_mfma_f32_16x16x32_bf16(ap, onesf, accS, 0, 0, 0);
        }
        const int nksB = ((cmax - cb0) >> 5) + 1;
        for (int ks = 0; ks < nksB; ++ks) {
            const int co = ks * 32 + quad * 8;
            bf16x8 ar = *(const bf16x8*)&PbB[(size_t)(rt * 16 + l16) * PBB_S + co];
            bf16x8 br = *(const bf16x8*)(rbase + cb0 + co);
            accB = __builtin_amdgcn_mfma_f32_16x16x32_bf16(ar, br, accB, 0, 0, 0);
            accSI = __builtin_amdgcn_mfma_f32_16x16x32_bf16(ar, onesf, accSI, 0, 0, 0);
        }
        const float rv0 = b2f(rbase[0]);      // relv[0][d]
        const float rv1 = b2f(rbase[1024]);   // relv[1024][d]
#pragma unroll
        for (int i = 0; i < 4; ++i) {
            const int row = rt * 16 + quad * 4 + i;
            const int q = q0 + row;
            const float tail = accS[i] - accSI[i];
            const float lowS = (q >= k0 + 512) ? tail : 0.f;
            const float highS = (q <= k0 - 257) ? tail : 0.f;
            const int R = bh * SEQ + q;
            float val = accA[i] + accB[i] + lowS * rv0 + highS * rv1;
            Opart[((size_t)R * 4 + quarter) * 64 + dq * 16 + l16] = __float2half(val);
        }
        if (dq == 0 && l16 == 0) {
#pragma unroll
            for (int i = 0; i < 4; ++i) {
                const int row = rt * 16 + quad * 4 + i;
                ms[(size_t)(bh * SEQ + q0 + row) * 4 + quarter] =
                    make_float2(mxS[row], accS[i]);
            }
        }
    }
}

// ---------------------------------------------------------------------------
// Kernel 4: combine the four k-quarters (flash-style rescale, exp2 domain).
// ---------------------------------------------------------------------------
__global__ __launch_bounds__(256) void sa_combine_kernel(
    const __half* __restrict__ Opart, const float2* __restrict__ ms,
    unsigned short* __restrict__ aob) {
    const int tid = threadIdx.x;
    const int R = blockIdx.x * 4 + (tid >> 6);
    const int d = tid & 63;
    float2 s[4];
#pragma unroll
    for (int j = 0; j < 4; ++j) s[j] = ms[(size_t)R * 4 + j];
    float m = fmaxf(fmaxf(s[0].x, s[1].x), fmaxf(s[2].x, s[3].x));
    float a[4], denom = 0.f;
#pragma unroll
    for (int j = 0; j < 4; ++j) {
        a[j] = EXP2F(s[j].x - m);
        denom += s[j].y * a[j];
    }
    float inv = 1.f / denom;
    float val = 0.f;
#pragma unroll
    for (int j = 0; j < 4; ++j)
        val += __half2float(Opart[((size_t)R * 4 + j) * 64 + d]) * a[j];
    val *= inv;
    const int bh = R >> 10, q = R & 1023, b = bh >> 4, h = bh & 15;
    aob[((size_t)b * SEQ + q) * EMB + h * 64 + d] = f2bu(val);
}

// ---------------------------------------------------------------------------
// Kernel 5: FC MFMA GEMM (unchanged). out = aob @ Wfc_b^T + bfc.
// ---------------------------------------------------------------------------
__global__ __launch_bounds__(256, 2) void sa_fc_kernel(
    const unsigned short* __restrict__ A, const unsigned short* __restrict__ W,
    const float* __restrict__ bias, float* __restrict__ out) {
    const int t = threadIdx.x;
    const int w = t >> 6, lane = t & 63;
    const int quad = lane >> 4, l16 = lane & 15;
    const int mw = blockIdx.x * 64 + (w & 1) * 32;
    const int nw = blockIdx.y * 256 + (w >> 1) * 128;

    floatx4 acc[2][8];
#pragma unroll
    for (int mt = 0; mt < 2; ++mt)
#pragma unroll
        for (int j = 0; j < 8; ++j) acc[mt][j] = floatx4{0.f, 0.f, 0.f, 0.f};
    float bj[8];
#pragma unroll
    for (int j = 0; j < 8; ++j) bj[j] = bias[nw + j * 16 + l16];

    for (int ks = 0; ks < 32; ++ks) {
        const int co = ks * 32 + quad * 8;
        bf16x8 af0 = *(const bf16x8*)(A + (size_t)(mw + l16) * EMB + co);
        bf16x8 af1 = *(const bf16x8*)(A + (size_t)(mw + 16 + l16) * EMB + co);
#pragma unroll
        for (int j = 0; j < 8; ++j) {
            bf16x8 bf = *(const bf16x8*)(W + (size_t)(nw + j * 16 + l16) * EMB + co);
            acc[0][j] = __builtin_amdgcn_mfma_f32_16x16x32_bf16(af0, bf, acc[0][j], 0, 0, 0);
            acc[1][j] = __builtin_amdgcn_mfma_f32_16x16x32_bf16(af1, bf, acc[1][j], 0, 0, 0);
        }
    }
#pragma unroll
    for (int mt = 0; mt < 2; ++mt)
#pragma unroll
        for (int j = 0; j < 8; ++j) {
            const int col = nw + j * 16 + l16;
#pragma unroll
            for (int i = 0; i < 4; ++i) {
                const size_t row = mw + mt * 16 + quad * 4 + i;
                out[row * EMB + col] = acc[mt][j][i] + bj[j];
            }
        }
}

extern "C" void kernel_launch(void* const* d_in, const int* in_sizes, int n_in,
                              void* d_out, int out_size, void* d_ws, size_t ws_size,
                              hipStream_t stream) {
    const float* query = (const float*)d_in[0];
    const float* key = (const float*)d_in[1];
    const float* value = (const float*)d_in[2];
    const int* mask = (const int*)d_in[3];
    const float* Wq = (const float*)d_in[4];
    const float* bq = (const float*)d_in[5];
    const float* Wk = (const float*)d_in[6];
    const float* bk = (const float*)d_in[7];
    const float* Wv = (const float*)d_in[8];
    const float* bv = (const float*)d_in[9];
    const float* Wfc = (const float*)d_in[10];
    const float* bfc = (const float*)d_in[11];
    const float* relk = (const float*)d_in[12];
    const float* relv = (const float*)d_in[13];
    float* out = (float*)d_out;

    char* base = (char*)d_ws;
    const size_t MB = (size_t)1 << 20;
    // Layout (aob overlays qb: qb is fully consumed by attn before combine
    // writes aob; stream order guarantees safety). Total ws use ~62.6 MB.
    unsigned short* qb = (unsigned short*)(base + 0 * MB);        // 8 MB
    unsigned short* aob = qb;                                     // overlay
    unsigned short* kb = (unsigned short*)(base + 8 * MB);        // 8 MB
    unsigned short* vtb = (unsigned short*)(base + 16 * MB);      // 8 MB
    unsigned short* wfcb = (unsigned short*)(base + 24 * MB);     // 2 MB
    unsigned short* relkb = (unsigned short*)(base + 26 * MB);                 // 133,120 B
    unsigned short* relvtb = (unsigned short*)(base + 26 * MB + 163840);       // 136,192 B
    unsigned short* wqb = (unsigned short*)(base + 26 * MB + 327680);          // 8 KB each
    unsigned short* wkb = (unsigned short*)(base + 26 * MB + 335872);
    unsigned short* wvb = (unsigned short*)(base + 26 * MB + 344064);
    unsigned* flags = (unsigned*)(base + 26 * MB + 360448);                    // 16 B
    unsigned* part = (unsigned*)(base + 26 * MB + 364544);                     // 1 KB
    float2* ms = (float2*)(base + 27 * MB);                                    // 2 MB
    __half* Opart = (__half*)(base + 29 * MB);                                 // 33.5 MB

    // prep FIRST: proj consumes bf16 weights; attn consumes rel tables+flags.
    sa_prep_kernel<<<CONV_BLOCKS + 256, 256, 0, stream>>>(
        Wfc, relk, relv, Wq, Wk, Wv, mask, wfcb, relkb, relvtb, wqb, wkb, wvb, part);
    sa_proj_kernel<<<dim3(1024, 3), 256, 0, stream>>>(
        query, key, value, wqb, wkb, wvb, bq, bk, bv, qb, kb, vtb);
    sa_maskred2<<<1, 64, 0, stream>>>(part, flags);
    sa_attn_kernel<<<64 * 32 * 4, 512, 0, stream>>>(
        qb, kb, vtb, mask, relkb, relvtb, flags, Opart, ms);
    sa_combine_kernel<<<(4 * HEADS * SEQ) / 4, 256, 0, stream>>>(Opart, ms, aob);
    sa_fc_kernel<<<dim3(64, 4), 256, 0, stream>>>(aob, wfcb, bfc, out);
}